// Round 5
// baseline (4111.517 us; speedup 1.0000x reference)
//
#include <hip/hip_runtime.h>

#define NT 512
#define TRAJ 4

constexpr int Lk = 200;
constexpr int NSTEPS = 100;

typedef float f32x2 __attribute__((ext_vector_type(2)));
typedef float f32x4 __attribute__((ext_vector_type(4)));
typedef short s16x8 __attribute__((ext_vector_type(8)));

#if __has_builtin(__builtin_elementwise_fma)
#define FMA2(a, b, c) __builtin_elementwise_fma((a), (b), (c))
#else
static __device__ __forceinline__ f32x2 fma2_(f32x2 a, f32x2 b, f32x2 c) {
    c.x = fmaf(a.x, b.x, c.x); c.y = fmaf(a.y, b.y, c.y); return c;
}
#define FMA2 fma2_
#endif

// Stable softplus, matches jax.nn.softplus in fp32: max(x,0) + log1p(exp(-|x|))
__device__ __forceinline__ float sp_act(float x) {
    return fmaxf(x, 0.0f) + log1pf(expf(-fabsf(x)));
}

// fp32 -> bf16 round-to-nearest-even
__device__ __forceinline__ unsigned short f2bf(float f) {
    union { float f; unsigned int u; } v; v.f = f;
    unsigned int u = v.u + 0x7FFFu + ((v.u >> 16) & 1u);
    return (unsigned short)(u >> 16);
}

// Pack fW3 [2048][128] fp32 -> bf16 B-fragments for mfma_f32_16x16x32_bf16.
// Slot s = (tile*4 + ks)*64 + lane holds 8 bf16: B[k = ks*32 + (lane>>4)*8 + j][n = tile*16 + (lane&15)]
// (identical layout to the round-4 kernel that verified correct)
__global__ void fw3_packb(const float* __restrict__ w, unsigned short* __restrict__ p) {
    const int s = blockIdx.x * 256 + threadIdx.x;   // 0..32767
    const int tg = s >> 8;
    const int ks = (s >> 6) & 3;
    const int l  = s & 63;
    const int n  = tg * 16 + (l & 15);
    const int k0 = ks * 32 + (l >> 4) * 8;
    unsigned short out[8];
    #pragma unroll
    for (int j = 0; j < 8; ++j) out[j] = f2bf(w[n * 128 + k0 + j]);
    *(uint4*)(p + (size_t)s * 8) = *(const uint4*)out;
}

// Stage global weight W[O][I] (row-major) into LDS transposed T[I][O].
template<int O, int I>
__device__ __forceinline__ void stage_T(const float* __restrict__ g, float* __restrict__ T) {
    for (int base = threadIdx.x * 4; base < O * I; base += NT * 4) {
        const float4 w = *(const float4*)(g + base);
        const int o = base / I;
        const int i = base % I;
        T[(i + 0) * O + o] = w.x;
        T[(i + 1) * O + o] = w.y;
        T[(i + 2) * O + o] = w.z;
        T[(i + 3) * O + o] = w.w;
    }
}

// out[t][o] = act(bias[o] + sum_i in[t][i] * T[i][o]); ACT: 0=none,1=softplus,2=relu
template<int I, int O, int ACT>
__device__ __forceinline__ void mlp_layer(const float* __restrict__ T,
                                          const float* __restrict__ bias,
                                          const float* __restrict__ in, int inStride,
                                          float* __restrict__ out, int outStride) {
    const int tid = threadIdx.x;
    constexpr int TOT = TRAJ * O;
    for (int e = tid; e < TOT; e += NT) {
        const int t = e / O;
        const int o = e % O;
        const float* inr = in + t * inStride;
        f32x2 a2; a2.x = bias[o]; a2.y = 0.0f;
        #pragma unroll 4
        for (int i = 0; i < I; i += 2) {
            f32x2 xv; xv.x = inr[i];        xv.y = inr[i + 1];
            f32x2 wv; wv.x = T[i * O + o];  wv.y = T[(i + 1) * O + o];
            a2 = FMA2(xv, wv, a2);
        }
        float acc = a2.x + a2.y;
        if (ACT == 1) acc = sp_act(acc);
        else if (ACT == 2) acc = fmaxf(acc, 0.0f);
        out[t * outStride + o] = acc;
    }
}

// Issue one streamed tile's 4 B-fragments into a static prefetch slot.
// S and SLOT must be literal constants (no runtime-indexed register arrays — R2 lesson).
#define ISSUE_TILE(S, SLOT) do {                                  \
    sbuf[SLOT][0] = wq[((wave * 16 + (S)) * 4 + 0) * 64];         \
    sbuf[SLOT][1] = wq[((wave * 16 + (S)) * 4 + 1) * 64];         \
    sbuf[SLOT][2] = wq[((wave * 16 + (S)) * 4 + 2) * 64];         \
    sbuf[SLOT][3] = wq[((wave * 16 + (S)) * 4 + 3) * 64];         \
} while (0)

// One output tile: 4 chained MFMAs + fused bias + dX einsum accumulation.
#define TILE_MFMA(TI, WA) do {                                                              \
    f32x4 acc_ = {0.f, 0.f, 0.f, 0.f};                                                      \
    acc_ = __builtin_amdgcn_mfma_f32_16x16x32_bf16(afrag[0], *(const s16x8*)&(WA)[0], acc_, 0, 0, 0); \
    acc_ = __builtin_amdgcn_mfma_f32_16x16x32_bf16(afrag[1], *(const s16x8*)&(WA)[1], acc_, 0, 0, 0); \
    acc_ = __builtin_amdgcn_mfma_f32_16x16x32_bf16(afrag[2], *(const s16x8*)&(WA)[2], acc_, 0, 0, 0); \
    acc_ = __builtin_amdgcn_mfma_f32_16x16x32_bf16(afrag[3], *(const s16x8*)&(WA)[3], acc_, 0, 0, 0); \
    const float bb_ = fb3s[(wave * 16 + (TI)) * 16 + (lane & 15)];                          \
    _Pragma("unroll")                                                                       \
    for (int r_ = 0; r_ < 4; ++r_) {                                                        \
        const float g_ = acc_[r_] + bb_;                                                    \
        psum[(TI) >> 1][r_] = fmaf(g_, ((TI) & 1) ? dx1[r_] : dx0[r_], psum[(TI) >> 1][r_]); \
    }                                                                                       \
} while (0)

__global__ __launch_bounds__(NT, 1)
void cde_kernel(const float* __restrict__ ts,
                const float* __restrict__ coef_d, const float* __restrict__ coef_c,
                const float* __restrict__ coef_b, const float* __restrict__ coef_a,
                const float* __restrict__ iW1, const float* __restrict__ ib1,
                const float* __restrict__ iW2, const float* __restrict__ ib2,
                const float* __restrict__ iW3, const float* __restrict__ ib3,
                const float* __restrict__ fW1, const float* __restrict__ fb1,
                const float* __restrict__ fW2, const float* __restrict__ fb2,
                const float* __restrict__ fb3,
                const float* __restrict__ dW1, const float* __restrict__ db1,
                const float* __restrict__ dW2, const float* __restrict__ db2,
                const float* __restrict__ dW3, const float* __restrict__ db3,
                const unsigned short* __restrict__ fW3B,
                float* __restrict__ outp)
{
    // wreg phase-union. Init: 28672 floats. Main: wT1(8192)+wT2(16384)=24576,
    // fb3s (2048 f) at +24576, h2f (2048 bf16 = 1024 f) at +26624. Decoder:
    // dT1+dT2+dT3 = 26624 (overlaps dead fb3s). LDS total 123904 B (proven size).
    __shared__ __align__(16) float wreg[28672];
    __shared__ float h1s[TRAJ * 128], h2s[TRAJ * 128];
    __shared__ float ys[TRAJ * 64], ys2[TRAJ * 64], k1s[TRAJ * 64];
    __shared__ float dXs[TRAJ * 32], a0s[TRAJ * 32];
    __shared__ float fb1s[128], fb2s[128];

    float* const fb3s = wreg + 24576;                              // [2048]
    unsigned short* const h2f = (unsigned short*)(wreg + 26624);   // [2048] bf16, fragment order

    const int tid  = threadIdx.x;
    const int lane = tid & 63;
    const int wave = tid >> 6;
    const int bbase = blockIdx.x * TRAJ;

    const float ts0 = ts[0];
    const float dt = (ts[Lk - 1] - ts0) / (float)NSTEPS;
    const float hdt = 0.5f * dt;
    const uint4* wq = (const uint4*)fW3B + lane;

    // ---- initial condition: y0 = sp(MLP_i(coef_a[:,0,:])) ----
    if (tid < TRAJ * 32) {
        const int t = tid >> 5, d = tid & 31;
        a0s[t * 32 + d] = coef_a[((size_t)(bbase + t) * 199) * 32 + d];
    }
    stage_T<128, 32>(iW1, wreg);                       // iT1 [32][128]
    stage_T<128, 128>(iW2, wreg + 32 * 128);           // iT2 [128][128]
    stage_T<64, 128>(iW3, wreg + 32 * 128 + 128 * 128);// iT3 [128][64]
    if (tid < 128) { fb1s[tid] = fb1[tid]; fb2s[tid] = fb2[tid]; }
    __syncthreads();
    mlp_layer<32, 128, 1>(wreg, ib1, a0s, 32, h1s, 128);
    __syncthreads();
    mlp_layer<128, 128, 1>(wreg + 32 * 128, ib2, h1s, 128, h2s, 128);
    __syncthreads();
    mlp_layer<128, 64, 1>(wreg + 32 * 128 + 128 * 128, ib3, h2s, 128, ys, 64);
    __syncthreads();

    // ---- stage vf weights + fb3 + zero h2f pad (resident for all 200 evals) ----
    stage_T<128, 64>(fW1, wreg);                       // wT1 [64][128]
    stage_T<128, 128>(fW2, wreg + 64 * 128);           // wT2 [128][128]
    for (int i = tid * 4; i < 2048; i += NT * 4)
        *(float4*)(fb3s + i) = *(const float4*)(fb3 + i);
    for (int i = tid; i < 2048; i += NT) h2f[i] = 0;   // rows t=4..15 stay zero
    __syncthreads();

    // ---- resident B-tiles: each wave keeps its tiles 0..3 in VGPRs (loaded once) ----
    uint4 res[4][4];
    #pragma unroll
    for (int ti = 0; ti < 4; ++ti)
        #pragma unroll
        for (int ks = 0; ks < 4; ++ks)
            res[ti][ks] = wq[((wave * 16 + ti) * 4 + ks) * 64];

    // ---- Heun, 100 steps = 200 evals; eval body fully inline ----
    #pragma unroll 1
    for (int e = 0; e < 2 * NSTEPS; ++e) {
        const bool k2e = e & 1;
        const float t1 = ts0 + (float)(e >> 1) * dt + (k2e ? dt : 0.0f);
        const float* yin   = k2e ? ys2 : ys;
        float*       yout  = k2e ? ys  : ys2;

        // cubic-spline derivative dX/dt at scalar time t1
        if (tid < TRAJ * 32) {
            int i = (int)floorf(t1);
            i = min(max(i, 0), Lk - 2);
            const float frac = t1 - ts[i];
            const int tt = tid >> 5, d = tid & 31;
            const size_t off = ((size_t)(bbase + tt) * 199 + (size_t)i) * 32 + d;
            dXs[tid] = coef_b[off] + frac * (2.0f * coef_c[off] + 3.0f * frac * coef_d[off]);
        }

        // prefetch ring (4 static slots, depth 3): tiles 4,5,6 issued here; their
        // latency hides under the two small MLP layers.
        uint4 sbuf[4][4];
        ISSUE_TILE(4, 0); ISSUE_TILE(5, 1); ISSUE_TILE(6, 2);

        mlp_layer<64, 128, 1>(wreg, fb1s, yin, 64, h1s, 128);
        __syncthreads();

        // layer2 -> bf16, written directly in MFMA A-fragment order:
        // h2f[((o>>3)*16 + t)*8 + (o&7)]
        {
            const int t = tid >> 7, o = tid & 127;
            const float* inr = h1s + t * 128;
            f32x2 a2; a2.x = fb2s[o]; a2.y = 0.0f;
            #pragma unroll 4
            for (int i = 0; i < 128; i += 2) {
                f32x2 xv; xv.x = inr[i];            xv.y = inr[i + 1];
                f32x2 wv; wv.x = wreg[64*128 + i*128 + o]; wv.y = wreg[64*128 + (i+1)*128 + o];
                a2 = FMA2(xv, wv, a2);
            }
            h2f[((o >> 3) * 16 + t) * 8 + (o & 7)] = f2bf(sp_act(a2.x + a2.y));
        }
        __syncthreads();

        // A-fragments, conflict-free: byte addr = lane*16 + ks*1024 (2 lanes/bank = free)
        s16x8 afrag[4];
        #pragma unroll
        for (int ks = 0; ks < 4; ++ks)
            afrag[ks] = *(const s16x8*)(h2f + ((ks * 4 + (lane >> 4)) * 16 + (lane & 15)) * 8);

        float dx0[4], dx1[4];
        #pragma unroll
        for (int r = 0; r < 4; ++r) {
            dx0[r] = dXs[r * 32 + (lane & 15)];
            dx1[r] = dXs[r * 32 + 16 + (lane & 15)];
        }

        float psum[8][4];
        #pragma unroll
        for (int h = 0; h < 8; ++h)
            #pragma unroll
            for (int r = 0; r < 4; ++r) psum[h][r] = 0.0f;

        // tiles 0-3: resident registers (no loads). tiles 4-15: streamed, issued 3 ahead.
        TILE_MFMA(0, res[0]);
        TILE_MFMA(1, res[1]);
        TILE_MFMA(2, res[2]);
        TILE_MFMA(3, res[3]);
        ISSUE_TILE(7, 3);   TILE_MFMA(4,  sbuf[0]);
        ISSUE_TILE(8, 0);   TILE_MFMA(5,  sbuf[1]);
        ISSUE_TILE(9, 1);   TILE_MFMA(6,  sbuf[2]);
        ISSUE_TILE(10, 2);  TILE_MFMA(7,  sbuf[3]);
        ISSUE_TILE(11, 3);  TILE_MFMA(8,  sbuf[0]);
        ISSUE_TILE(12, 0);  TILE_MFMA(9,  sbuf[1]);
        ISSUE_TILE(13, 1);  TILE_MFMA(10, sbuf[2]);
        ISSUE_TILE(14, 2);  TILE_MFMA(11, sbuf[3]);
        ISSUE_TILE(15, 3);  TILE_MFMA(12, sbuf[0]);
        TILE_MFMA(13, sbuf[1]);
        TILE_MFMA(14, sbuf[2]);
        TILE_MFMA(15, sbuf[3]);

        // Reduce over d: butterfly within each 16-lane group (real data in lanes 0-15).
        #pragma unroll
        for (int m = 1; m < 16; m <<= 1)
            #pragma unroll
            for (int h = 0; h < 8; ++h)
                #pragma unroll
                for (int r = 0; r < 4; ++r)
                    psum[h][r] += __shfl_xor(psum[h][r], m, 64);

        // Owner lanes write k and the fused Heun update. h global = wave*8 + h.
        #pragma unroll
        for (int h = 0; h < 8; ++h) {
            if (lane == h) {
                const int hg = wave * 8 + h;
                #pragma unroll
                for (int r = 0; r < 4; ++r) {
                    const int idx = r * 64 + hg;
                    const float kq = psum[h][r];
                    if (!k2e) { k1s[idx] = kq; yout[idx] = ys[idx] + dt * kq; }
                    else      {                yout[idx] = ys[idx] + hdt * (k1s[idx] + kq); }
                }
            }
        }
        __syncthreads();
    }

    // ---- decoder: Linear->relu->Linear->relu->Linear ----
    stage_T<128, 64>(dW1, wreg);                          // dT1 [64][128]
    stage_T<128, 128>(dW2, wreg + 64 * 128);              // dT2 [128][128]
    stage_T<16, 128>(dW3, wreg + 64 * 128 + 128 * 128);   // dT3 [128][16] (overlaps dead fb3s)
    __syncthreads();
    mlp_layer<64, 128, 2>(wreg, db1, ys, 64, h1s, 128);
    __syncthreads();
    mlp_layer<128, 128, 2>(wreg + 64 * 128, db2, h1s, 128, h2s, 128);
    __syncthreads();
    mlp_layer<128, 16, 0>(wreg + 64 * 128 + 128 * 128, db3, h2s, 128,
                          outp + (size_t)bbase * 16, 16);
}

extern "C" void kernel_launch(void* const* d_in, const int* in_sizes, int n_in,
                              void* d_out, int out_size, void* d_ws, size_t ws_size,
                              hipStream_t stream) {
    (void)in_sizes; (void)n_in; (void)out_size; (void)ws_size;
    const float* ts     = (const float*)d_in[0];
    const float* coef_d = (const float*)d_in[1];
    const float* coef_c = (const float*)d_in[2];
    const float* coef_b = (const float*)d_in[3];
    const float* coef_a = (const float*)d_in[4];
    const float* iW1 = (const float*)d_in[5];  const float* ib1 = (const float*)d_in[6];
    const float* iW2 = (const float*)d_in[7];  const float* ib2 = (const float*)d_in[8];
    const float* iW3 = (const float*)d_in[9];  const float* ib3 = (const float*)d_in[10];
    const float* fW1 = (const float*)d_in[11]; const float* fb1 = (const float*)d_in[12];
    const float* fW2 = (const float*)d_in[13]; const float* fb2 = (const float*)d_in[14];
    const float* fW3 = (const float*)d_in[15]; const float* fb3 = (const float*)d_in[16];
    const float* dW1 = (const float*)d_in[17]; const float* db1 = (const float*)d_in[18];
    const float* dW2 = (const float*)d_in[19]; const float* db2 = (const float*)d_in[20];
    const float* dW3 = (const float*)d_in[21]; const float* db3 = (const float*)d_in[22];

    unsigned short* fW3B = (unsigned short*)d_ws;   // 512 KB: fW3 as bf16 B-fragments

    fw3_packb<<<128, 256, 0, stream>>>(fW3, fW3B);
    cde_kernel<<<256, NT, 0, stream>>>(ts, coef_d, coef_c, coef_b, coef_a,
                                       iW1, ib1, iW2, ib2, iW3, ib3,
                                       fW1, fb1, fW2, fb2, fb3,
                                       dW1, db1, dW2, db2, dW3, db3,
                                       fW3B, (float*)d_out);
}

// Round 7
// 2960.384 us; speedup vs baseline: 1.3888x; 1.3888x over previous
//
#include <hip/hip_runtime.h>

#define NT 512
#define TRAJ 2

constexpr int Lk = 200;
constexpr int NSTEPS = 100;

typedef float f32x2 __attribute__((ext_vector_type(2)));

#if __has_builtin(__builtin_elementwise_fma)
#define FMA2(a, b, c) __builtin_elementwise_fma((a), (b), (c))
#else
static __device__ __forceinline__ f32x2 fma2_(f32x2 a, f32x2 b, f32x2 c) {
    c.x = fmaf(a.x, b.x, c.x); c.y = fmaf(a.y, b.y, c.y); return c;
}
#define FMA2 fma2_
#endif

// Stable softplus, matches jax.nn.softplus in fp32: max(x,0) + log1p(exp(-|x|))
__device__ __forceinline__ float sp_act(float x) {
    return fmaxf(x, 0.0f) + log1pf(expf(-fabsf(x)));
}

// fp32 -> bf16 round-to-nearest-even (returned in low 16 bits)
__device__ __forceinline__ unsigned int f2bf(float f) {
    union { float f; unsigned int u; } v; v.f = f;
    unsigned int u = v.u + 0x7FFFu + ((v.u >> 16) & 1u);
    return u >> 16;
}
// bf16 pair (packed in a uint) -> two f32
__device__ __forceinline__ float bflo(unsigned int u) { return __uint_as_float(u << 16); }
__device__ __forceinline__ float bfhi(unsigned int u) { return __uint_as_float(u & 0xFFFF0000u); }

// Pack fW3 [2048][128] f32 -> bf16, thread-owned layout (R0's proven address pattern):
// uint4 slot s = c*512 + town  (c = ko*4 + j) holds w[n = 4*town + j][k = ko*8 .. ko*8+7].
// Main kernel reads wq[c*512] with wq = base + tid -> lane-contiguous 16B, fully coalesced,
// and all blocks sweep the 512 KB buffer in the same order (L2-friendly; FETCH stays ~MB).
__global__ void fw3_packbf(const float* __restrict__ w, uint4* __restrict__ p) {
    const int s = blockIdx.x * 256 + threadIdx.x;   // 0..32767
    const int town = s & 511;
    const int c = s >> 9;           // 0..63
    const int j = c & 3, ko = c >> 2;
    const int n = 4 * town + j;
    const float4 a = *(const float4*)(w + n * 128 + ko * 8);
    const float4 b = *(const float4*)(w + n * 128 + ko * 8 + 4);
    uint4 o;
    o.x = f2bf(a.x) | (f2bf(a.y) << 16);
    o.y = f2bf(a.z) | (f2bf(a.w) << 16);
    o.z = f2bf(b.x) | (f2bf(b.y) << 16);
    o.w = f2bf(b.z) | (f2bf(b.w) << 16);
    p[s] = o;
}

// Stage global W[O][I] (f32 row-major) -> LDS transposed f32 T[I][O].
template<int O, int I>
__device__ __forceinline__ void stage_T(const float* __restrict__ g, float* __restrict__ T) {
    for (int base = threadIdx.x * 4; base < O * I; base += NT * 4) {
        const float4 w = *(const float4*)(g + base);
        const int o = base / I;
        const int i = base % I;
        T[(i + 0) * O + o] = w.x;
        T[(i + 1) * O + o] = w.y;
        T[(i + 2) * O + o] = w.z;
        T[(i + 3) * O + o] = w.w;
    }
}

// Stage global W[O][I] -> LDS bf16-pair-transposed: Tp[(i/2)*O + o] = pack(w[o][i], w[o][i+1])
template<int O, int I>
__device__ __forceinline__ void stage_Tp(const float* __restrict__ g, unsigned int* __restrict__ Tp) {
    for (int base = threadIdx.x * 2; base < O * I; base += NT * 2) {
        const float2 w = *(const float2*)(g + base);
        const int o = base / I;
        const int i = base % I;          // even
        Tp[(i >> 1) * O + o] = f2bf(w.x) | (f2bf(w.y) << 16);
    }
}

// f32-weight layer: out[t][o] = act(bias[o] + sum_i in[t][i]*T[i][o])
template<int I, int O, int ACT>
__device__ __forceinline__ void mlp_layer(const float* __restrict__ T,
                                          const float* __restrict__ bias,
                                          const float* __restrict__ in, int inStride,
                                          float* __restrict__ out, int outStride) {
    const int tid = threadIdx.x;
    constexpr int TOT = TRAJ * O;
    for (int e = tid; e < TOT; e += NT) {
        const int t = e / O;
        const int o = e % O;
        const float* inr = in + t * inStride;
        f32x2 a2; a2.x = bias[o]; a2.y = 0.0f;
        #pragma unroll 4
        for (int i = 0; i < I; i += 2) {
            f32x2 xv; xv.x = inr[i];        xv.y = inr[i + 1];
            f32x2 wv; wv.x = T[i * O + o];  wv.y = T[(i + 1) * O + o];
            a2 = FMA2(xv, wv, a2);
        }
        float acc = a2.x + a2.y;
        if (ACT == 1) acc = sp_act(acc);
        else if (ACT == 2) acc = fmaxf(acc, 0.0f);
        out[t * outStride + o] = acc;
    }
}

// bf16-pair-weight layer. OMAJOR=1 writes out[o*TRAJ + t] (k-major pairs for the big layer).
template<int I, int O, int ACT, int OMAJOR>
__device__ __forceinline__ void mlp_layer_p(const unsigned int* __restrict__ Tp,
                                            const float* __restrict__ bias,
                                            const float* __restrict__ in, int inStride,
                                            float* __restrict__ out, int outStride) {
    const int tid = threadIdx.x;
    constexpr int TOT = TRAJ * O;
    for (int e = tid; e < TOT; e += NT) {
        const int t = e / O;
        const int o = e % O;
        const float* inr = in + t * inStride;
        f32x2 a2; a2.x = bias[o]; a2.y = 0.0f;
        #pragma unroll 4
        for (int ip = 0; ip < I / 2; ++ip) {
            const unsigned int u = Tp[ip * O + o];
            f32x2 xv = *(const f32x2*)(inr + 2 * ip);
            f32x2 wv; wv.x = bflo(u); wv.y = bfhi(u);
            a2 = FMA2(xv, wv, a2);
        }
        float acc = a2.x + a2.y;
        if (ACT == 1) acc = sp_act(acc);
        else if (ACT == 2) acc = fmaxf(acc, 0.0f);
        if (OMAJOR) out[o * TRAJ + t] = acc;
        else        out[t * outStride + o] = acc;
    }
}

__global__ __launch_bounds__(NT, 4)
void cde_kernel(const float* __restrict__ ts,
                const float* __restrict__ coef_d, const float* __restrict__ coef_c,
                const float* __restrict__ coef_b, const float* __restrict__ coef_a,
                const float* __restrict__ iW1, const float* __restrict__ ib1,
                const float* __restrict__ iW2, const float* __restrict__ ib2,
                const float* __restrict__ iW3, const float* __restrict__ ib3,
                const float* __restrict__ fW1, const float* __restrict__ fb1,
                const float* __restrict__ fW2, const float* __restrict__ fb2,
                const float* __restrict__ fb3,
                const float* __restrict__ dW1, const float* __restrict__ db1,
                const float* __restrict__ dW2, const float* __restrict__ db2,
                const float* __restrict__ dW3, const float* __restrict__ db3,
                const uint4* __restrict__ fW3B,
                float* __restrict__ outp)
{
    // R is a phase union, 17408 words = 69632 B (R6 bug: was 16896 -> dT3p overflowed):
    //  init:    iT1 f32 [32][128] @0 (4096) | iT2p @4096 (8192) | iT3p @12288 (4096)
    //  main:    wT1 f32 [64][128] @0 (8192) | wT2p @8192 (8192)
    //  decoder: dT1 f32 @0 (8192) | dT2p @8192 (8192) | dT3p @16384 (1024) -> 17408 OK
    // Total LDS ~75.8 KB -> 2 blocks/CU (the occupancy thesis under test).
    __shared__ __align__(16) float R[17408];
    __shared__ __align__(16) float h1s[TRAJ * 128];
    __shared__ __align__(16) float hbuf[TRAJ * 128];
    __shared__ __align__(16) float h2T[128 * TRAJ];   // [k][t] pairs
    __shared__ __align__(16) float ys[TRAJ * 64], ys2[TRAJ * 64], k1s[TRAJ * 64];
    __shared__ __align__(16) float dXsT[32 * TRAJ];   // [d][t] pairs
    __shared__ __align__(16) float a0s[TRAJ * 32];
    __shared__ __align__(16) float fb1s[128], fb2s[128];

    const int tid = threadIdx.x;
    const int bbase = blockIdx.x * TRAJ;

    const float ts0 = ts[0];
    const float dt = (ts[Lk - 1] - ts0) / (float)NSTEPS;
    const float hdt = 0.5f * dt;
    const float4 fb3r = *((const float4*)fb3 + tid);     // n = 4*tid .. 4*tid+3
    const uint4* wq = fW3B + tid;                        // row stride 512 uint4

    // ---- initial condition: y0 = sp(MLP_i(coef_a[:,0,:])) ----
    if (tid < TRAJ * 32) {
        const int t = tid >> 5, d = tid & 31;
        a0s[t * 32 + d] = coef_a[((size_t)(bbase + t) * 199) * 32 + d];
    }
    stage_T<128, 32>(iW1, R);                                  // iT1
    stage_Tp<128, 128>(iW2, (unsigned int*)(R + 4096));        // iT2p
    stage_Tp<64, 128>(iW3, (unsigned int*)(R + 12288));        // iT3p
    if (tid < 128) { fb1s[tid] = fb1[tid]; fb2s[tid] = fb2[tid]; }
    __syncthreads();
    mlp_layer<32, 128, 1>(R, ib1, a0s, 32, h1s, 128);
    __syncthreads();
    mlp_layer_p<128, 128, 1, 0>((unsigned int*)(R + 4096), ib2, h1s, 128, hbuf, 128);
    __syncthreads();
    mlp_layer_p<128, 64, 1, 0>((unsigned int*)(R + 12288), ib3, hbuf, 128, ys, 64);
    __syncthreads();

    // ---- stage vector-field weights (resident for all 200 evals) ----
    stage_T<128, 64>(fW1, R);                                  // wT1 f32
    stage_Tp<128, 128>(fW2, (unsigned int*)(R + 8192));        // wT2p bf16
    __syncthreads();

    // ---- Heun, 100 steps = 200 evals ----
    #pragma unroll 1
    for (int e = 0; e < 2 * NSTEPS; ++e) {
        const bool k2e = e & 1;
        const float t1 = ts0 + (float)(e >> 1) * dt + (k2e ? dt : 0.0f);
        const float* yin  = k2e ? ys2 : ys;
        float*       yout = k2e ? ys  : ys2;

        // cubic-spline derivative dX/dt, stored traj-paired: dXsT[d][t]
        if (tid < TRAJ * 32) {
            int i = (int)floorf(t1);
            i = min(max(i, 0), Lk - 2);
            const float frac = t1 - ts[i];
            const int t = tid >> 5, d = tid & 31;
            const size_t off = ((size_t)(bbase + t) * 199 + (size_t)i) * 32 + d;
            dXsT[d * TRAJ + t] = coef_b[off] + frac * (2.0f * coef_c[off] + 3.0f * frac * coef_d[off]);
        }

        mlp_layer<64, 128, 1>(R, fb1s, yin, 64, h1s, 128);
        __syncthreads();
        // layer2 -> h2T[k][t] (traj pairs, k-major) for packed big-layer FMAs
        mlp_layer_p<128, 128, 1, 1>((unsigned int*)(R + 8192), fb2s, h1s, 128, h2T, TRAJ);
        __syncthreads();

        // Big layer: thread owns n = 4*tid+j. acc[j] = (out[t0][n], out[t1][n]),
        // bias folded into init. Weights stream bf16 from L2 in R0's address pattern.
        f32x2 acc0, acc1, acc2, acc3;
        acc0.x = acc0.y = fb3r.x;
        acc1.x = acc1.y = fb3r.y;
        acc2.x = acc2.y = fb3r.z;
        acc3.x = acc3.y = fb3r.w;

        #pragma unroll 2
        for (int ko = 0; ko < 16; ++ko) {
            const uint4 u0 = wq[(ko * 4 + 0) * 512];
            const uint4 u1 = wq[(ko * 4 + 1) * 512];
            const uint4 u2 = wq[(ko * 4 + 2) * 512];
            const uint4 u3 = wq[(ko * 4 + 3) * 512];
            const float* hp = h2T + ko * 8 * TRAJ;
            f32x2 h[8];
            #pragma unroll
            for (int q = 0; q < 8; ++q) h[q] = *(const f32x2*)(hp + q * TRAJ);
            #pragma unroll
            for (int q = 0; q < 4; ++q) {
                const unsigned int w0 = (q == 0) ? u0.x : (q == 1) ? u0.y : (q == 2) ? u0.z : u0.w;
                const unsigned int w1 = (q == 0) ? u1.x : (q == 1) ? u1.y : (q == 2) ? u1.z : u1.w;
                const unsigned int w2 = (q == 0) ? u2.x : (q == 1) ? u2.y : (q == 2) ? u2.z : u2.w;
                const unsigned int w3 = (q == 0) ? u3.x : (q == 1) ? u3.y : (q == 2) ? u3.z : u3.w;
                f32x2 s;
                s.x = s.y = bflo(w0); acc0 = FMA2(h[2 * q], s, acc0);
                s.x = s.y = bfhi(w0); acc0 = FMA2(h[2 * q + 1], s, acc0);
                s.x = s.y = bflo(w1); acc1 = FMA2(h[2 * q], s, acc1);
                s.x = s.y = bfhi(w1); acc1 = FMA2(h[2 * q + 1], s, acc1);
                s.x = s.y = bflo(w2); acc2 = FMA2(h[2 * q], s, acc2);
                s.x = s.y = bfhi(w2); acc2 = FMA2(h[2 * q + 1], s, acc2);
                s.x = s.y = bflo(w3); acc3 = FMA2(h[2 * q], s, acc3);
                s.x = s.y = bfhi(w3); acc3 = FMA2(h[2 * q + 1], s, acc3);
            }
        }

        // einsum over d: n=4*tid+j -> h = tid>>3, d = 4*(tid&7)+j; traj pair in lanes of acc
        const int dj = 4 * (tid & 7);
        f32x2 part; part.x = part.y = 0.0f;
        part = FMA2(acc0, *(const f32x2*)(dXsT + (dj + 0) * TRAJ), part);
        part = FMA2(acc1, *(const f32x2*)(dXsT + (dj + 1) * TRAJ), part);
        part = FMA2(acc2, *(const f32x2*)(dXsT + (dj + 2) * TRAJ), part);
        part = FMA2(acc3, *(const f32x2*)(dXsT + (dj + 3) * TRAJ), part);

        float px = part.x, py = part.y;
        #pragma unroll
        for (int m = 1; m < 8; m <<= 1) {
            px += __shfl_xor(px, m, 64);
            py += __shfl_xor(py, m, 64);
        }

        // owner lanes: write k1 and fused Heun update
        if ((tid & 7) == 0) {
            const int h = tid >> 3;     // 0..63
            if (!k2e) {
                k1s[h] = px;      yout[h]      = ys[h]      + dt * px;
                k1s[64 + h] = py; yout[64 + h] = ys[64 + h] + dt * py;
            } else {
                yout[h]      = ys[h]      + hdt * (k1s[h] + px);
                yout[64 + h] = ys[64 + h] + hdt * (k1s[64 + h] + py);
            }
        }
        __syncthreads();
    }

    // ---- decoder: Linear->relu->Linear->relu->Linear ----
    stage_T<128, 64>(dW1, R);                                  // dT1 f32
    stage_Tp<128, 128>(dW2, (unsigned int*)(R + 8192));        // dT2p
    stage_Tp<16, 128>(dW3, (unsigned int*)(R + 16384));        // dT3p (1024 uints, fits now)
    __syncthreads();
    mlp_layer<64, 128, 2>(R, db1, ys, 64, h1s, 128);
    __syncthreads();
    mlp_layer_p<128, 128, 2, 0>((unsigned int*)(R + 8192), db2, h1s, 128, hbuf, 128);
    __syncthreads();
    mlp_layer_p<128, 16, 0, 0>((unsigned int*)(R + 16384), db3, hbuf, 128,
                               outp + (size_t)bbase * 16, 16);
}

extern "C" void kernel_launch(void* const* d_in, const int* in_sizes, int n_in,
                              void* d_out, int out_size, void* d_ws, size_t ws_size,
                              hipStream_t stream) {
    (void)in_sizes; (void)n_in; (void)out_size; (void)ws_size;
    const float* ts     = (const float*)d_in[0];
    const float* coef_d = (const float*)d_in[1];
    const float* coef_c = (const float*)d_in[2];
    const float* coef_b = (const float*)d_in[3];
    const float* coef_a = (const float*)d_in[4];
    const float* iW1 = (const float*)d_in[5];  const float* ib1 = (const float*)d_in[6];
    const float* iW2 = (const float*)d_in[7];  const float* ib2 = (const float*)d_in[8];
    const float* iW3 = (const float*)d_in[9];  const float* ib3 = (const float*)d_in[10];
    const float* fW1 = (const float*)d_in[11]; const float* fb1 = (const float*)d_in[12];
    const float* fW2 = (const float*)d_in[13]; const float* fb2 = (const float*)d_in[14];
    const float* fW3 = (const float*)d_in[15]; const float* fb3 = (const float*)d_in[16];
    const float* dW1 = (const float*)d_in[17]; const float* db1 = (const float*)d_in[18];
    const float* dW2 = (const float*)d_in[19]; const float* db2 = (const float*)d_in[20];
    const float* dW3 = (const float*)d_in[21]; const float* db3 = (const float*)d_in[22];

    uint4* fW3B = (uint4*)d_ws;   // 512 KB: fW3 bf16, thread-owned layout

    fw3_packbf<<<128, 256, 0, stream>>>(fW3, fW3B);
    cde_kernel<<<512, NT, 0, stream>>>(ts, coef_d, coef_c, coef_b, coef_a,
                                       iW1, ib1, iW2, ib2, iW3, ib3,
                                       fW1, fb1, fW2, fb2, fb3,
                                       dW1, db1, dW2, db2, dW3, db3,
                                       fW3B, (float*)d_out);
}